// Round 1
// baseline (4925.084 us; speedup 1.0000x reference)
//
#include <hip/hip_runtime.h>
#include <math.h>

// ---------------------------------------------------------------------------
// RbfNet: continuous conv GNN.
// Pipeline:
//   1. zero counts
//   2. repack weights: Wp[k][cq][co][4]  (k=0..63 from cw, k=64 from fw), fp32
//   3. edge histogram by receiver (skip self edges: mask in reference)
//   4. single-block scan -> offsets + cursor
//   5. edge scatter -> CSR records {j | iu<<17 | iv<<20, (fu,fv)}
//   6. conv layer 0  (Cin=4,  Cout=32, concat [lin|conv])          -> ansA
//   7. conv layer 1  (Cin=64, Cout=64, relu in)                    -> ansB
//   8. conv layer 2  (Cin=64, Cout=64, relu in, +residual)         -> ansA
//   9. conv layer 3  (Cin=64, Cout=2,  relu in, /128)              -> d_out
// Conv kernel: 4 nodes/WG (1 node/wave), fp32 moments [4][64][Cin] in LDS
// (<= 64 KB), lane = channel so no atomics needed; then mom@W with
// broadcast LDS reads + coalesced float4 W loads.
// ---------------------------------------------------------------------------

__device__ __forceinline__ float clampf(float x, float lo, float hi) {
    return fminf(fmaxf(x, lo), hi);
}

__global__ void zero_ints(int* __restrict__ p, int n) {
    int i = blockIdx.x * 256 + threadIdx.x;
    if (i < n) p[i] = 0;
}

// Wp flat index: ((k*CQ + cq)*COUT + co)*4 + cc   where c = cq*4+cc
__global__ void repack_w(const float* __restrict__ cw, const float* __restrict__ fw,
                         float* __restrict__ Wp, int CIN, int COUT) {
    int e = blockIdx.x * 256 + threadIdx.x;
    int total = 65 * CIN * COUT;
    if (e >= total) return;
    int cc = e & 3;
    int rest = e >> 2;
    int co = rest % COUT;
    int rest2 = rest / COUT;
    int CQ = CIN >> 2;
    int cq = rest2 % CQ;
    int k = rest2 / CQ;
    int c = cq * 4 + cc;
    float v = (k < 64) ? cw[(k * CIN + c) * COUT + co] : fw[c * COUT + co];
    Wp[e] = v;
}

__global__ void edge_hist(const int* __restrict__ ei, const int* __restrict__ ej,
                          int* __restrict__ counts, int E) {
    int e = blockIdx.x * 256 + threadIdx.x;
    if (e >= E) return;
    int i = ei[e], j = ej[e];
    if (i != j) atomicAdd(&counts[i], 1);
}

__global__ __launch_bounds__(1024) void scan_kernel(const int* __restrict__ counts,
                                                    int* __restrict__ offs,
                                                    int* __restrict__ cursor, int N) {
    __shared__ int sums[1024];
    const int t = threadIdx.x;
    const int per = (N + 1023) / 1024;
    const int lo = t * per;
    const int hi = min(lo + per, N);
    int s = 0;
    for (int i = lo; i < hi; ++i) s += counts[i];
    sums[t] = s;
    __syncthreads();
    for (int d = 1; d < 1024; d <<= 1) {
        int v = (t >= d) ? sums[t - d] : 0;
        __syncthreads();
        sums[t] += v;
        __syncthreads();
    }
    int run = (t > 0) ? sums[t - 1] : 0;
    for (int i = lo; i < hi; ++i) {
        offs[i] = run;
        cursor[i] = run;
        run += counts[i];
    }
    if (t == 1023) offs[N] = sums[1023];
}

__global__ void edge_scatter(const int* __restrict__ ei, const int* __restrict__ ej,
                             const float* __restrict__ pos, int* __restrict__ cursor,
                             int* __restrict__ csr_jk, float2* __restrict__ csr_w, int E) {
    int e = blockIdx.x * 256 + threadIdx.x;
    if (e >= E) return;
    int i = ei[e], j = ej[e];
    if (i == j) return;
    float dx = clampf(pos[i * 2 + 0] - pos[j * 2 + 0], -1.f, 1.f);
    float dy = clampf(pos[i * 2 + 1] - pos[j * 2 + 1], -1.f, 1.f);
    float r = sqrtf(dx * dx + dy * dy + 1e-12f);
    float u = clampf(2.f * r - 1.f, -1.f, 1.f);
    float v = atan2f(dy, dx) * 0.3183098861837907f;  // / pi
    float tu = (u + 1.f) * 3.5f;                     // / (2/7)
    float tv = (v + 1.f) * 3.5f;
    int iu = min(6, max(0, (int)floorf(tu)));
    int iv = min(6, max(0, (int)floorf(tv)));
    float fu = clampf(tu - (float)iu, 0.f, 1.f);
    float fv = clampf(tv - (float)iv, 0.f, 1.f);
    int p = atomicAdd(&cursor[i], 1);
    csr_jk[p] = j | (iu << 17) | (iv << 20);
    csr_w[p] = make_float2(fu, fv);
}

// MODE 0: layer0  (no relu on input; out = [lin(0..31) | conv(32..63)])
// MODE 1: relu in, out = conv + cb + a@fw + fb
// MODE 2: MODE1 + residual (x pre-relu)
// MODE 3: relu in, Cout=2, out = (conv + cb + a@fw + fb) / 128
template <int CIN, int COUT, int MODE>
__global__ __launch_bounds__(256, 1) void conv_kernel(
    const float* __restrict__ x, const float* __restrict__ Wp,
    const float* __restrict__ cb, const float* __restrict__ fb,
    const int* __restrict__ offs, const int* __restrict__ csr_jk,
    const float2* __restrict__ csr_w, float* __restrict__ out, int nNodes) {
    constexpr int TM = 4;
    constexpr int CQ = CIN / 4;
    extern __shared__ float mom[];  // [TM][64][CIN]
    const int tid = threadIdx.x;
    const int wave = tid >> 6;
    const int lane = tid & 63;
    const int base = blockIdx.x * TM;
    const int n = base + wave;

    {  // zero moments
        const int tot4 = TM * 64 * CIN / 4;
        float4* m4 = (float4*)mom;
        for (int i = tid; i < tot4; i += 256) m4[i] = make_float4(0.f, 0.f, 0.f, 0.f);
    }
    __syncthreads();

    // ---------------- scatter: one wave owns one node, one lane owns channel c
    if (n < nNodes) {
        const int s0 = offs[n], e0 = offs[n + 1];
        float* momn = mom + wave * 64 * CIN;
        const int c = lane;
        for (int b = s0; b < e0; b += 4) {
            const int cnt = min(4, e0 - b);
            int jk[4];
            float2 wv[4];
            float xv[4];
#pragma unroll
            for (int q = 0; q < 4; ++q)
                if (q < cnt) {
                    jk[q] = csr_jk[b + q];
                    wv[q] = csr_w[b + q];
                }
#pragma unroll
            for (int q = 0; q < 4; ++q)
                if (q < cnt) {
                    int j = jk[q] & 0x1FFFF;
                    float xvv = (c < CIN) ? x[j * CIN + c] : 0.f;
                    if (MODE >= 1) xvv = fmaxf(xvv, 0.f);
                    xv[q] = xvv;
                }
#pragma unroll
            for (int q = 0; q < 4; ++q)
                if (q < cnt && c < CIN) {
                    int iu = (jk[q] >> 17) & 7, iv = (jk[q] >> 20) & 7;
                    float fu = wv[q].x, fv = wv[q].y;
                    float gu = 1.f - fu, gv = 1.f - fv;
                    float* p = momn + (iu * 8 + iv) * CIN + c;
                    p[0] += gu * gv * xv[q];
                    p[CIN] += gu * fv * xv[q];
                    p[8 * CIN] += fu * gv * xv[q];
                    p[9 * CIN] += fu * fv * xv[q];
                }
        }
    }
    __syncthreads();

    // ---------------- contraction
    const float* mw = mom + wave * 64 * CIN;

    if (MODE == 1 || MODE == 2) {
        const int co = lane;  // COUT == 64
        float acc = 0.f;
        for (int k = 0; k < 64; ++k) {
            const float4* mrow = (const float4*)(mw + k * CIN);
#pragma unroll
            for (int cq = 0; cq < CQ; ++cq) {
                float4 w4 = *(const float4*)(Wp + (((k * CQ + cq) * COUT) + co) * 4);
                float4 a = mrow[cq];
                acc += a.x * w4.x + a.y * w4.y + a.z * w4.z + a.w * w4.w;
            }
        }
        if (n < nNodes) {
            const float4* xrow = (const float4*)(x + n * CIN);
#pragma unroll
            for (int cq = 0; cq < CQ; ++cq) {
                float4 w4 = *(const float4*)(Wp + (((64 * CQ + cq) * COUT) + co) * 4);
                float4 a = xrow[cq];
                a.x = fmaxf(a.x, 0.f);
                a.y = fmaxf(a.y, 0.f);
                a.z = fmaxf(a.z, 0.f);
                a.w = fmaxf(a.w, 0.f);
                acc += a.x * w4.x + a.y * w4.y + a.z * w4.z + a.w * w4.w;
            }
            float res = acc + cb[co] + fb[co];
            if (MODE == 2) res += x[n * COUT + co];
            out[n * COUT + co] = res;
        }
    } else if (MODE == 0) {
        // CIN=4, CQ=1, COUT=32; lanes 0..31: conv -> cols 32..63; lanes 32..63: lin -> cols 0..31
        const int half = lane >> 5;
        const int co = lane & 31;
        if (n < nNodes) {
            if (half == 0) {
                float acc = 0.f;
                for (int k = 0; k < 64; ++k) {
                    float4 w4 = *(const float4*)(Wp + ((k * 32) + co) * 4);
                    float4 a = *(const float4*)(mw + k * 4);
                    acc += a.x * w4.x + a.y * w4.y + a.z * w4.z + a.w * w4.w;
                }
                out[n * 64 + 32 + co] = acc + cb[co];
            } else {
                float4 w4 = *(const float4*)(Wp + ((64 * 32) + co) * 4);
                float4 a = *(const float4*)(x + n * 4);
                out[n * 64 + co] = a.x * w4.x + a.y * w4.y + a.z * w4.z + a.w * w4.w + fb[co];
            }
        }
    } else if (MODE == 3) {
        // COUT=2: co = lane&1, split k over lane>>1, shuffle-reduce
        const int co = lane & 1;
        const int kp = lane >> 1;  // 0..31
        float acc = 0.f;
#pragma unroll
        for (int kk = 0; kk < 2; ++kk) {
            int k = kp + kk * 32;
#pragma unroll
            for (int cq = 0; cq < 16; ++cq) {
                float4 w4 = *(const float4*)(Wp + (((k * 16 + cq) * 2) + co) * 4);
                float4 a = *(const float4*)(mw + k * 64 + cq * 4);
                acc += a.x * w4.x + a.y * w4.y + a.z * w4.z + a.w * w4.w;
            }
        }
        acc += __shfl_xor(acc, 2);
        acc += __shfl_xor(acc, 4);
        acc += __shfl_xor(acc, 8);
        acc += __shfl_xor(acc, 16);
        acc += __shfl_xor(acc, 32);
        if (kp == 0 && n < nNodes) {
            float accf = 0.f;
            const float4* xrow = (const float4*)(x + n * 64);
#pragma unroll
            for (int cq = 0; cq < 16; ++cq) {
                float4 w4 = *(const float4*)(Wp + (((64 * 16 + cq) * 2) + co) * 4);
                float4 a = xrow[cq];
                a.x = fmaxf(a.x, 0.f);
                a.y = fmaxf(a.y, 0.f);
                a.z = fmaxf(a.z, 0.f);
                a.w = fmaxf(a.w, 0.f);
                accf += a.x * w4.x + a.y * w4.y + a.z * w4.z + a.w * w4.w;
            }
            out[n * 2 + co] = (acc + accf + cb[co] + fb[co]) * (1.f / 128.f);
        }
    }
}

extern "C" void kernel_launch(void* const* d_in, const int* in_sizes, int n_in,
                              void* d_out, int out_size, void* d_ws, size_t ws_size,
                              hipStream_t stream) {
    const float* pos = (const float*)d_in[0];
    const float* feat = (const float*)d_in[1];
    const int* ei = (const int*)d_in[2];
    const int* ej = (const int*)d_in[3];
    const float* cw0 = (const float*)d_in[4];
    const float* cb0 = (const float*)d_in[5];
    const float* fw0 = (const float*)d_in[6];
    const float* fb0 = (const float*)d_in[7];
    const float* cw1 = (const float*)d_in[8];
    const float* cb1 = (const float*)d_in[9];
    const float* fw1 = (const float*)d_in[10];
    const float* fb1 = (const float*)d_in[11];
    const float* cw2 = (const float*)d_in[12];
    const float* cb2 = (const float*)d_in[13];
    const float* fw2 = (const float*)d_in[14];
    const float* fb2 = (const float*)d_in[15];
    const float* cw3 = (const float*)d_in[16];
    const float* cb3 = (const float*)d_in[17];
    const float* fw3 = (const float*)d_in[18];
    const float* fb3 = (const float*)d_in[19];
    float* outp = (float*)d_out;

    const int N = in_sizes[0] / 2;
    const int E = in_sizes[2];

    char* wsp = (char*)d_ws;
    size_t off = 0;
    auto alloc = [&](size_t bytes) -> void* {
        void* p = wsp + off;
        off = (off + bytes + 255) & ~(size_t)255;
        return p;
    };
    int* counts = (int*)alloc((size_t)N * 4);
    int* offs = (int*)alloc((size_t)(N + 1) * 4);
    int* cursor = (int*)alloc((size_t)N * 4);
    int* csr_jk = (int*)alloc((size_t)E * 4);
    float2* csr_w = (float2*)alloc((size_t)E * 8);
    float* ansA = (float*)alloc((size_t)N * 64 * 4);
    float* ansB = (float*)alloc((size_t)N * 64 * 4);
    float* Wp0 = (float*)alloc((size_t)65 * 4 * 32 * 4);
    float* Wp1 = (float*)alloc((size_t)65 * 64 * 64 * 4);
    float* Wp2 = (float*)alloc((size_t)65 * 64 * 64 * 4);
    float* Wp3 = (float*)alloc((size_t)65 * 64 * 2 * 4);
    (void)ws_size;
    (void)n_in;
    (void)out_size;

    zero_ints<<<dim3((N + 255) / 256), dim3(256), 0, stream>>>(counts, N);
    repack_w<<<dim3((65 * 4 * 32 + 255) / 256), dim3(256), 0, stream>>>(cw0, fw0, Wp0, 4, 32);
    repack_w<<<dim3((65 * 64 * 64 + 255) / 256), dim3(256), 0, stream>>>(cw1, fw1, Wp1, 64, 64);
    repack_w<<<dim3((65 * 64 * 64 + 255) / 256), dim3(256), 0, stream>>>(cw2, fw2, Wp2, 64, 64);
    repack_w<<<dim3((65 * 64 * 2 + 255) / 256), dim3(256), 0, stream>>>(cw3, fw3, Wp3, 64, 2);
    edge_hist<<<dim3((E + 255) / 256), dim3(256), 0, stream>>>(ei, ej, counts, E);
    scan_kernel<<<dim3(1), dim3(1024), 0, stream>>>(counts, offs, cursor, N);
    edge_scatter<<<dim3((E + 255) / 256), dim3(256), 0, stream>>>(ei, ej, pos, cursor, csr_jk,
                                                                  csr_w, E);

    const int blocks = (N + 3) / 4;
    conv_kernel<4, 32, 0><<<dim3(blocks), dim3(256), 4 * 64 * 4 * 4, stream>>>(
        feat, Wp0, cb0, fb0, offs, csr_jk, csr_w, ansA, N);
    conv_kernel<64, 64, 1><<<dim3(blocks), dim3(256), 4 * 64 * 64 * 4, stream>>>(
        ansA, Wp1, cb1, fb1, offs, csr_jk, csr_w, ansB, N);
    conv_kernel<64, 64, 2><<<dim3(blocks), dim3(256), 4 * 64 * 64 * 4, stream>>>(
        ansB, Wp2, cb2, fb2, offs, csr_jk, csr_w, ansA, N);
    conv_kernel<64, 2, 3><<<dim3(blocks), dim3(256), 4 * 64 * 64 * 4, stream>>>(
        ansA, Wp3, cb3, fb3, offs, csr_jk, csr_w, outp, N);
}